// Round 8
// baseline (341.673 us; speedup 1.0000x reference)
//
#include <hip/hip_runtime.h>
#include <hip/hip_fp8.h>
#include <math.h>

#define N_NODES 100000
#define N_EDGES 1600000
#define F_IN 256
#define F_H 128
#define F_OUT 40

// ---- CSR build via LDS-binned counting sort ----
#define BIN_SHIFT 9
#define BIN_NODES 512                       // 1 << BIN_SHIFT
#define NBIN 196                            // ceil(100000 / 512)
#define CAP 12288                           // per-bin capacity (mean 8163, sigma ~90)
#define CNT_PAD 16                          // one counter per 64B line
#define PART_CHUNK 8192                     // edges per k_part block

typedef __attribute__((ext_vector_type(8))) short bf16x8;
typedef __attribute__((ext_vector_type(4))) float floatx4;
typedef __attribute__((ext_vector_type(2))) float floatx2;
typedef __attribute__((ext_vector_type(2))) unsigned int uintx2;
typedef __attribute__((ext_vector_type(4))) unsigned int uintx4;

__device__ __forceinline__ unsigned short f2bf(float f) {
    unsigned int u = __float_as_uint(f);
    u += 0x7fffu + ((u >> 16) & 1u);          // RNE (finite inputs)
    return (unsigned short)(u >> 16);
}

// ---- fp8 e4m3 (OCP) encode/decode, native cvt when available ----
#if defined(__has_builtin)
#if __has_builtin(__builtin_amdgcn_cvt_pk_fp8_f32)
#define HAVE_PK_ENC 1
#endif
#if __has_builtin(__builtin_amdgcn_cvt_pk_f32_fp8)
#define HAVE_PK_DEC 1
#endif
#if __has_builtin(__builtin_amdgcn_cvt_f32_fp8)
#define HAVE_SC_DEC 1
#endif
#endif

__device__ __forceinline__ unsigned char f2f8(float f) {
#ifdef HAVE_PK_ENC
    int r = __builtin_amdgcn_cvt_pk_fp8_f32(f, f, 0, false);
    return (unsigned char)(r & 0xff);
#else
    __hip_fp8_e4m3 t(f);
    return (unsigned char)t.__x;
#endif
}
__device__ __forceinline__ float f82f(unsigned char b) {
#ifdef HAVE_SC_DEC
    return __builtin_amdgcn_cvt_f32_fp8((int)b, 0);
#else
    __hip_fp8_e4m3 t; t.__x = (__hip_fp8_storage_t)b;
    return (float)t;
#endif
}
__device__ __forceinline__ floatx2 f8x2tof(unsigned short u) {
#ifdef HAVE_PK_DEC
    return __builtin_amdgcn_cvt_pk_f32_fp8((int)u, false);
#else
    floatx2 r;
    r.x = f82f((unsigned char)(u & 0xff));
    r.y = f82f((unsigned char)(u >> 8));
    return r;
#endif
}

// accumulate 16 fp8 (one uint4) into a[0..15]
__device__ __forceinline__ void acc16(uintx4 u, float* a) {
#pragma unroll
    for (int d = 0; d < 4; ++d) {
        floatx2 lo = f8x2tof((unsigned short)(u[d] & 0xffffu));
        floatx2 hi = f8x2tof((unsigned short)(u[d] >> 16));
        a[d * 4 + 0] += lo.x; a[d * 4 + 1] += lo.y;
        a[d * 4 + 2] += hi.x; a[d * 4 + 3] += hi.y;
    }
}

// ---- phase A: partition edges into NBIN dst-bins (packed src<<9|dloc) ----
__global__ __launch_bounds__(256) void k_part(const int* __restrict__ eidx,
                                              int* __restrict__ gcnt,
                                              unsigned int* __restrict__ parts) {
    __shared__ int hist[4][NBIN];
    __shared__ int sbase[NBIN];
    __shared__ int rcnt[NBIN];
    const int tid = threadIdx.x;
    const int wv = tid >> 6;
    for (int i = tid; i < NBIN; i += 256) {
        hist[0][i] = 0; hist[1][i] = 0; hist[2][i] = 0; hist[3][i] = 0; rcnt[i] = 0;
    }
    __syncthreads();
    const int e0 = blockIdx.x * PART_CHUNK;
    const int e1 = min(e0 + PART_CHUNK, N_EDGES);
    for (int e = e0 + tid; e < e1; e += 256) {
        int d = eidx[N_EDGES + e];
        atomicAdd(&hist[wv][d >> BIN_SHIFT], 1);
    }
    __syncthreads();
    for (int b = tid; b < NBIN; b += 256) {
        int tot = hist[0][b] + hist[1][b] + hist[2][b] + hist[3][b];
        int old = atomicAdd(&gcnt[b * CNT_PAD], tot);
        sbase[b] = b * CAP + old;
    }
    __syncthreads();
    for (int e = e0 + tid; e < e1; e += 256) {
        int d = eidx[N_EDGES + e];          // L2-hot re-read
        int s = eidx[e];
        int b = d >> BIN_SHIFT;
        int r = atomicAdd(&rcnt[b], 1);
        parts[sbase[b] + r] = ((unsigned int)s << BIN_SHIFT) | (unsigned int)(d & (BIN_NODES - 1));
    }
}

// ---- phase B: per-bin CSR build; block g owns nodes [g*512, g*512+512) ----
__global__ __launch_bounds__(256) void k_build(const unsigned int* __restrict__ parts,
                                               const int* __restrict__ gcnt,
                                               int* __restrict__ rowptr,
                                               float* __restrict__ dinv,
                                               int* __restrict__ csr_src) {
    __shared__ int deg[4][BIN_NODES];   // per-wave replicated histogram (8 KB)
    __shared__ int cur[BIN_NODES];
    __shared__ int scan[256];
    const int tid = threadIdx.x;
    const int wv = tid >> 6;
    const int g = blockIdx.x;

    // exclusive scan of bin sizes -> this bin's global edge base
    scan[tid] = (tid < NBIN) ? gcnt[tid * CNT_PAD] : 0;
    __syncthreads();
    for (int off = 1; off < 256; off <<= 1) {
        int v = 0;
        if (tid >= off) v = scan[tid - off];
        __syncthreads();
        if (tid >= off) scan[tid] += v;
        __syncthreads();
    }
    const int binBase = (g == 0) ? 0 : scan[g - 1];
    const int cntg = scan[g] - binBase;

    for (int i = tid; i < BIN_NODES; i += 256) {
        deg[0][i] = 0; deg[1][i] = 0; deg[2][i] = 0; deg[3][i] = 0;
    }
    __syncthreads();

    const unsigned int* pp = parts + (size_t)g * CAP;
    for (int i = tid; i < cntg; i += 256)
        atomicAdd(&deg[wv][pp[i] & (BIN_NODES - 1)], 1);
    __syncthreads();

    // block scan over 512 degrees (thread t owns nodes 2t, 2t+1)
    const int n0 = 2 * tid, n1 = 2 * tid + 1;
    const int d0 = deg[0][n0] + deg[1][n0] + deg[2][n0] + deg[3][n0];
    const int d1 = deg[0][n1] + deg[1][n1] + deg[2][n1] + deg[3][n1];
    scan[tid] = d0 + d1;
    __syncthreads();
    for (int off = 1; off < 256; off <<= 1) {
        int v = 0;
        if (tid >= off) v = scan[tid - off];
        __syncthreads();
        if (tid >= off) scan[tid] += v;
        __syncthreads();
    }
    const int pre = (tid == 0) ? 0 : scan[tid - 1];
    const int p0 = binBase + pre;
    const int p1 = p0 + d0;
    const int node0 = g * BIN_NODES + n0;
    if (node0 < N_NODES)     { rowptr[node0]     = p0; dinv[node0]     = rsqrtf((float)d0 + 1.0f); }
    if (node0 + 1 < N_NODES) { rowptr[node0 + 1] = p1; dinv[node0 + 1] = rsqrtf((float)d1 + 1.0f); }
    cur[n0] = p0;
    cur[n1] = p1;
    __syncthreads();

    for (int i = tid; i < cntg; i += 256) {
        unsigned int u = pp[i];
        int pos = atomicAdd(&cur[u & (BIN_NODES - 1)], 1);
        csr_src[pos] = (int)(u >> BIN_SHIFT);
    }
    if (g == NBIN - 1 && tid == 0) rowptr[N_NODES] = N_EDGES;
}

// ---- weight converts + gcnt zero (runs FIRST): W1t [128][256], W2t [48][128] ----
__global__ void k_cvt_w(const float* __restrict__ W1, const float* __restrict__ W2,
                        short* __restrict__ W1t, short* __restrict__ W2t,
                        int* __restrict__ gcnt) {
    int b = blockIdx.x, t = threadIdx.x;
    if (b < 128) {
        int idx = b * 256 + t;                 // 32768
        int n = idx >> 8, k = idx & 255;
        W1t[n * 256 + k] = (short)f2bf(W1[k * 128 + n]);
    } else {
        int idx = (b - 128) * 256 + t;         // 6144
        if (idx < 48 * 128) {
            int n = idx >> 7, k = idx & 127;
            float v = (n < F_OUT) ? W2[k * F_OUT + n] : 0.f;
            W2t[n * 128 + k] = (short)f2bf(v);
        }
        int z = (b - 128) * 256 + t;           // 24 blocks x 256 = 6144 >= 3136
        if (z < NBIN * CNT_PAD) gcnt[z] = 0;
    }
}

// ---- GEMM1 (MFMA bf16, gemm2-style): h1f8[N,128](fp8) = dinv[row]*(x@W1) ----
// 128-row tile. Full-K B staged into LDS once; A staged per 32-k step.
__global__ __launch_bounds__(256) void k_gemm1_mfma(const float* __restrict__ x,
                                                    const short* __restrict__ W1t,
                                                    const float* __restrict__ dinv,
                                                    unsigned char* __restrict__ h1f8) {
    __shared__ short As[128 * 40];       // 10 KB, row stride 40 (80 B: 2-way banks, free)
    __shared__ short Bs[128 * 264];      // 67.6 KB, row stride 264
    __shared__ float Ds[128];
    const int tid = threadIdx.x;
    const int row0 = blockIdx.x * 128;
    const int w = tid >> 6, l = tid & 63;
    const int l15 = l & 15, q = l >> 4;
    const int ar = tid >> 1;             // 0..127
    const int ak = (tid & 1) * 16;       // 0 or 16

    // stage full B once: thread t covers row n=t>>1, k-half (t&1)*128
    {
        const int n = tid >> 1;
        const int kh = (tid & 1) * 128;
#pragma unroll
        for (int i = 0; i < 16; ++i)
            *(bf16x8*)&Bs[n * 264 + kh + i * 8] = *(const bf16x8*)&W1t[n * 256 + kh + i * 8];
    }
    if (tid < 128) {
        int r = row0 + tid;
        Ds[tid] = (r < N_NODES) ? dinv[r] : 0.f;
    }

    floatx4 acc[2][8];
#pragma unroll
    for (int a = 0; a < 2; ++a)
#pragma unroll
        for (int nt = 0; nt < 8; ++nt) acc[a][nt] = (floatx4)0.f;

    const bool arow_ok = (row0 + ar) < N_NODES;
    const float* xp = x + (size_t)(row0 + ar) * F_IN;

    for (int k0 = 0; k0 < F_IN; k0 += 32) {
        bf16x8 av0 = (bf16x8)0, av1 = (bf16x8)0;
        if (arow_ok) {
            floatx4 f0 = *(const floatx4*)(xp + k0 + ak);
            floatx4 f1 = *(const floatx4*)(xp + k0 + ak + 4);
            floatx4 f2 = *(const floatx4*)(xp + k0 + ak + 8);
            floatx4 f3 = *(const floatx4*)(xp + k0 + ak + 12);
            av0[0] = (short)f2bf(f0[0]); av0[1] = (short)f2bf(f0[1]);
            av0[2] = (short)f2bf(f0[2]); av0[3] = (short)f2bf(f0[3]);
            av0[4] = (short)f2bf(f1[0]); av0[5] = (short)f2bf(f1[1]);
            av0[6] = (short)f2bf(f1[2]); av0[7] = (short)f2bf(f1[3]);
            av1[0] = (short)f2bf(f2[0]); av1[1] = (short)f2bf(f2[1]);
            av1[2] = (short)f2bf(f2[2]); av1[3] = (short)f2bf(f2[3]);
            av1[4] = (short)f2bf(f3[0]); av1[5] = (short)f2bf(f3[1]);
            av1[6] = (short)f2bf(f3[2]); av1[7] = (short)f2bf(f3[3]);
        }
        __syncthreads();              // also covers the one-time B stage on k0==0
        *(bf16x8*)&As[ar * 40 + ak]     = av0;
        *(bf16x8*)&As[ar * 40 + ak + 8] = av1;
        __syncthreads();

        bf16x8 af[2], bfr[8];
#pragma unroll
        for (int a = 0; a < 2; ++a)
            af[a] = *(const bf16x8*)&As[((w * 2 + a) * 16 + l15) * 40 + q * 8];
#pragma unroll
        for (int nt = 0; nt < 8; ++nt)
            bfr[nt] = *(const bf16x8*)&Bs[(nt * 16 + l15) * 264 + k0 + q * 8];
#pragma unroll
        for (int a = 0; a < 2; ++a)
#pragma unroll
            for (int nt = 0; nt < 8; ++nt)
                acc[a][nt] = __builtin_amdgcn_mfma_f32_16x16x32_bf16(af[a], bfr[nt], acc[a][nt], 0, 0, 0);
    }
#pragma unroll
    for (int a = 0; a < 2; ++a) {
#pragma unroll
        for (int r = 0; r < 4; ++r) {
            const int rl = (w * 2 + a) * 16 + q * 4 + r;
            const int row = row0 + rl;
            if (row < N_NODES) {
                const float ds = Ds[rl];
                unsigned char* hp = h1f8 + (size_t)row * F_H;
#pragma unroll
                for (int nt = 0; nt < 8; ++nt)
                    hp[nt * 16 + l15] = f2f8(acc[a][nt][r] * ds);
            }
        }
    }
}

// ---- FUSED SpMM1 + GEMM2: block owns 64 nodes ----
// Phase 1: 4 lanes/node gather h1 rows (2x uint4 per lane per edge), accumulate
//   agg1 = relu(dinv*sum + b1) in regs, write bf16 rows to LDS [64][132].
// Phase 2: wave w MFMAs its 16-node tile vs W2 (LDS), h2f8 = dinv*(agg1@W2).
// Eliminates the 25.6 MB agg1b HBM write + 25.6 MB read of the split version.
__global__ __launch_bounds__(256) void k_spmm1_gemm2(const int* __restrict__ rowptr,
                                                     const int* __restrict__ csr_src,
                                                     const uintx4* __restrict__ h1d4,  // fp8 rows as 8 uint4
                                                     const float* __restrict__ dinv,
                                                     const float* __restrict__ b1,
                                                     const short* __restrict__ W2t,
                                                     unsigned char* __restrict__ h2f8) {
    __shared__ short Bs[48 * 136];          // 12.75 KB
    __shared__ unsigned int aggs[64 * 66];  // 16.5 KB: 64 rows x 132 shorts (128 + pad 4)
    __shared__ float Ds[64];
    const int tid = threadIdx.x;

    // stage W2 (visibility guaranteed by the phase-1/2 barrier)
#pragma unroll
    for (int i = 0; i < 3; ++i) {
        int c = tid * 3 + i;                 // 0..767 chunks of 8 bf16
        int n = c >> 4, koff = (c & 15) * 8;
        *(bf16x8*)&Bs[n * 136 + koff] = *(const bf16x8*)&W2t[n * 128 + koff];
    }

    // bijective XCD-contiguous swizzle over 1563 blocks (1563 = 3*196 + 5*195)
    const int bid = blockIdx.x;
    const int kx = bid & 7, jx = bid >> 3;
    const int nb = (kx < 3) ? (kx * 196 + jx) : (3 * 196 + (kx - 3) * 195 + jx);

    const int slot = tid >> 2;               // 0..63 node slot
    const int p = tid & 2 ? (tid & 3) : (tid & 3);   // 0..3 (32B quarter)
    const int pq = tid & 3;
    const int node = nb * 64 + slot;
    const bool valid = node < N_NODES;
    const int nd = valid ? node : 0;
    const int beg = rowptr[nd];
    const int end = valid ? rowptr[nd + 1] : beg;
    const float dv = dinv[nd];
    if (pq == 0) Ds[slot] = valid ? dv : 0.f;

    float accA[32], accB[32];
#pragma unroll
    for (int jj = 0; jj < 32; ++jj) { accA[jj] = 0.f; accB[jj] = 0.f; }

    const size_t rb = (size_t)nd * 8 + pq * 2;
    {   // self loop
        uintx4 u0 = h1d4[rb];
        uintx4 u1 = h1d4[rb + 1];
        acc16(u0, accA); acc16(u1, &accA[16]);
    }
    int i = beg;
    for (; i + 1 < end; i += 2) {
        int s0 = csr_src[i], s1 = csr_src[i + 1];
        uintx4 u0 = h1d4[(size_t)s0 * 8 + pq * 2];
        uintx4 u1 = h1d4[(size_t)s0 * 8 + pq * 2 + 1];
        uintx4 u2 = h1d4[(size_t)s1 * 8 + pq * 2];
        uintx4 u3 = h1d4[(size_t)s1 * 8 + pq * 2 + 1];
        acc16(u0, accA); acc16(u1, &accA[16]);
        acc16(u2, accB); acc16(u3, &accB[16]);
    }
    if (i < end) {
        int s0 = csr_src[i];
        uintx4 u0 = h1d4[(size_t)s0 * 8 + pq * 2];
        uintx4 u1 = h1d4[(size_t)s0 * 8 + pq * 2 + 1];
        acc16(u0, accA); acc16(u1, &accA[16]);
    }

    // phase-1 epilogue: relu(fma) -> bf16 pairs -> LDS row
    {
        const float* bp = b1 + 32 * pq;
        unsigned int* arow = &aggs[slot * 66 + pq * 16];
#pragma unroll
        for (int jj = 0; jj < 16; ++jj) {
            float v0 = fmaf(accA[2 * jj]     + accB[2 * jj],     dv, bp[2 * jj]);
            float v1 = fmaf(accA[2 * jj + 1] + accB[2 * jj + 1], dv, bp[2 * jj + 1]);
            v0 = v0 > 0.f ? v0 : 0.f;
            v1 = v1 > 0.f ? v1 : 0.f;
            arow[jj] = ((unsigned int)f2bf(v1) << 16) | f2bf(v0);
        }
    }
    __syncthreads();

    // phase 2: 64x128 @ 128x48 MFMA; wave w owns rows [w*16, w*16+16)
    const int w = tid >> 6, l = tid & 63;
    const int l15 = l & 15, q = l >> 4;
    const short* aggsS = (const short*)aggs;

    floatx4 acc2[3];
#pragma unroll
    for (int nt = 0; nt < 3; ++nt) acc2[nt] = (floatx4)0.f;

#pragma unroll
    for (int k0 = 0; k0 < F_H; k0 += 32) {
        bf16x8 af = *(const bf16x8*)&aggsS[(w * 16 + l15) * 132 + k0 + q * 8];
        bf16x8 bfr[3];
#pragma unroll
        for (int nt = 0; nt < 3; ++nt)
            bfr[nt] = *(const bf16x8*)&Bs[(nt * 16 + l15) * 136 + k0 + q * 8];
#pragma unroll
        for (int nt = 0; nt < 3; ++nt)
            acc2[nt] = __builtin_amdgcn_mfma_f32_16x16x32_bf16(af, bfr[nt], acc2[nt], 0, 0, 0);
    }
#pragma unroll
    for (int nt = 0; nt < 3; ++nt) {
        const int col = nt * 16 + l15;
#pragma unroll
        for (int r = 0; r < 4; ++r) {
            const int rl = w * 16 + q * 4 + r;
            const int row = nb * 64 + rl;
            if (row < N_NODES && col < F_OUT)
                h2f8[(size_t)row * F_OUT + col] = f2f8(acc2[nt][r] * Ds[rl]);
        }
    }
}

// ---- SpMM2 + log_softmax: QUARTER-WAVE (16 lanes) per node; lanes 0..9 load dwords ----
__global__ __launch_bounds__(256) void k_spmm2_lsm(const int* __restrict__ rowptr,
                                                   const int* __restrict__ csr_src,
                                                   const unsigned int* __restrict__ h2d,  // fp8 rows as 10 dwords
                                                   const float* __restrict__ dinv,
                                                   const float* __restrict__ b2,
                                                   float* __restrict__ out) {
    const int qid = threadIdx.x >> 4;         // 0..15 node slot in block
    const int p = threadIdx.x & 15;           // dword index (active p<10)
    int node = blockIdx.x * 16 + qid;
    bool nvalid = node < N_NODES;
    bool valid = nvalid && (p < 10);
    int nd = nvalid ? node : 0;
    int beg = 0, end = 0;
    if (valid) { beg = rowptr[nd]; end = rowptr[nd + 1]; }
    float dv = dinv[nd];

    float A0 = 0.f, A1 = 0.f, A2 = 0.f, A3 = 0.f;
    float B0 = 0.f, B1 = 0.f, B2 = 0.f, B3 = 0.f;
    if (valid) {
        unsigned int su = h2d[(size_t)nd * 10 + p];
        floatx2 t0 = f8x2tof((unsigned short)(su & 0xffffu));
        floatx2 t1 = f8x2tof((unsigned short)(su >> 16));
        A0 = t0.x; A1 = t0.y; A2 = t1.x; A3 = t1.y;   // self loop
    }
    int i = beg;
    for (; i + 1 < end; i += 2) {
        int s0 = csr_src[i], s1 = csr_src[i + 1];
        unsigned int u0 = h2d[(size_t)s0 * 10 + p];
        unsigned int u1 = h2d[(size_t)s1 * 10 + p];
        floatx2 a01 = f8x2tof((unsigned short)(u0 & 0xffffu));
        floatx2 a23 = f8x2tof((unsigned short)(u0 >> 16));
        floatx2 b01 = f8x2tof((unsigned short)(u1 & 0xffffu));
        floatx2 b23 = f8x2tof((unsigned short)(u1 >> 16));
        A0 += a01.x; A1 += a01.y; A2 += a23.x; A3 += a23.y;
        B0 += b01.x; B1 += b01.y; B2 += b23.x; B3 += b23.y;
    }
    if (i < end) {
        unsigned int u0 = h2d[(size_t)csr_src[i] * 10 + p];
        floatx2 a01 = f8x2tof((unsigned short)(u0 & 0xffffu));
        floatx2 a23 = f8x2tof((unsigned short)(u0 >> 16));
        A0 += a01.x; A1 += a01.y; A2 += a23.x; A3 += a23.y;
    }

    float v0 = -INFINITY, v1 = -INFINITY, v2 = -INFINITY, v3 = -INFINITY;
    if (valid) {
        float4 bb = *(const float4*)&b2[4 * p];
        v0 = fmaf(A0 + B0, dv, bb.x);
        v1 = fmaf(A1 + B1, dv, bb.y);
        v2 = fmaf(A2 + B2, dv, bb.z);
        v3 = fmaf(A3 + B3, dv, bb.w);
    }
    float m = fmaxf(fmaxf(v0, v1), fmaxf(v2, v3));
#pragma unroll
    for (int off = 1; off < 16; off <<= 1) m = fmaxf(m, __shfl_xor(m, off, 16));
    float e = 0.f;
    if (valid) e = expf(v0 - m) + expf(v1 - m) + expf(v2 - m) + expf(v3 - m);
#pragma unroll
    for (int off = 1; off < 16; off <<= 1) e += __shfl_xor(e, off, 16);
    if (valid) {
        float ls = logf(e);
        floatx4 o;
        o[0] = v0 - m - ls; o[1] = v1 - m - ls; o[2] = v2 - m - ls; o[3] = v3 - m - ls;
        __builtin_nontemporal_store(o, (floatx4*)&out[(size_t)node * F_OUT + 4 * p]);
    }
}

extern "C" void kernel_launch(void* const* d_in, const int* in_sizes, int n_in,
                              void* d_out, int out_size, void* d_ws, size_t ws_size,
                              hipStream_t stream) {
    const float* x = (const float*)d_in[0];
    const int* eidx = (const int*)d_in[1];   // int32 from harness
    const float* W1 = (const float*)d_in[2];
    const float* b1 = (const float*)d_in[3];
    const float* W2 = (const float*)d_in[4];
    const float* b2 = (const float*)d_in[5];
    float* out = (float*)d_out;

    char* ws = (char*)d_ws;
    int*   gcnt      = (int*)  (ws);                 // NBIN*CNT_PAD ints (12.5 KB)
    int*   rowptr    = (int*)  (ws + 400512);        // 100001 ints
    int*   csr_src   = (int*)  (ws + 1200528);       // 1.6M ints
    float* dinv      = (float*)(ws + 7600528);       // 100000
    short* W1t       = (short*)(ws + 8000528);       // 32768 bf16
    short* W2t       = (short*)(ws + 8066064);       // 6144 bf16
    unsigned char*  h1f8  = (unsigned char*) (ws + 8078352);   // 12.8M fp8 (12.8 MB)
    unsigned int*   parts = (unsigned int*)  (ws + 20878352);  // 9.6 MB (dead after k_build)
    unsigned char*  h2f8  = (unsigned char*) (ws + 46478352);  // 4M fp8 (4 MB)

    k_cvt_w<<<152, 256, 0, stream>>>(W1, W2, W1t, W2t, gcnt);
    k_part<<<(N_EDGES + PART_CHUNK - 1) / PART_CHUNK, 256, 0, stream>>>(eidx, gcnt, parts);
    k_build<<<NBIN, 256, 0, stream>>>(parts, gcnt, rowptr, dinv, csr_src);

    k_gemm1_mfma<<<(N_NODES + 127) / 128, 256, 0, stream>>>(x, W1t, dinv, h1f8);
    k_spmm1_gemm2<<<1563, 256, 0, stream>>>(rowptr, csr_src,
                                            (const uintx4*)h1f8, dinv, b1, W2t, h2f8);
    k_spmm2_lsm<<<(N_NODES + 15) / 16, 256, 0, stream>>>(rowptr, csr_src,
                                                         (const unsigned int*)h2f8, dinv, b2, out);
}